// Round 3
// baseline (357.463 us; speedup 1.0000x reference)
//
#include <hip/hip_runtime.h>
#include <hip/hip_bf16.h>

#define N_SRC 50000
#define N_DST 50000
#define NEDGE 800000
#define IND   128
#define HEADS 4
#define CDIM  64
#define HC    256   // HEADS*CDIM
#define NB_SCAN 49  // ceil(50000/1024)

typedef _Float16 half8 __attribute__((ext_vector_type(8)));
typedef float    f32x4 __attribute__((ext_vector_type(4)));

// ---------------------------------------------------------------------------
// prep: [0,391) zero deg+cnt; [391,395) fold W·att; [395,523) W_src -> WhT fp16
__global__ void prep_kernel(const float* __restrict__ Wsrc, const float* __restrict__ Wdst,
                            const float* __restrict__ att_s, const float* __restrict__ att_d,
                            float* __restrict__ WsA, float* __restrict__ WdA,
                            _Float16* __restrict__ WhT, int* __restrict__ deg) {
    int b = blockIdx.x, tid = threadIdx.x;
    if (b < 391) {
        int i = b * 256 + tid;
        if (i < 2 * N_DST) deg[i] = 0;
    } else if (b < 395) {
        int id = (b - 391) * 256 + tid;   // 0..1023
        const float* W = (id < 512) ? Wsrc : Wdst;
        const float* A = (id < 512) ? att_s : att_d;
        float* O       = (id < 512) ? WsA  : WdA;
        int q = id & 511;
        int k = q >> 2, h = q & 3;
        float acc = 0.f;
        for (int c = 0; c < CDIM; ++c)
            acc += W[k * HC + h * CDIM + c] * A[h * CDIM + c];
        O[q] = acc;   // q == k*4+h
    } else {
        int idx = (b - 395) * 256 + tid;  // 0..32767, WhT[n][k] = W[k][n]
        int n = idx >> 7, k = idx & 127;
        WhT[idx] = (_Float16)Wsrc[k * HC + n];
    }
}

// ---------------------------------------------------------------------------
// Per-node attention logits: a[n][h] = x[n,:] . WA[:,h].  One wave per node.
__global__ __launch_bounds__(256) void node_alpha_kernel(
        const float* __restrict__ x_src, const float* __restrict__ x_dst,
        const float* __restrict__ WsA, const float* __restrict__ WdA,
        float* __restrict__ a_s, float* __restrict__ a_d) {
    int gw   = (blockIdx.x * 256 + threadIdx.x) >> 6;
    int lane = threadIdx.x & 63;
    const float* xp; const float4* wa; float* op; int n;
    if (gw < N_SRC) { n = gw;         xp = x_src + (size_t)n * IND; wa = (const float4*)WsA; op = a_s; }
    else            { n = gw - N_SRC; xp = x_dst + (size_t)n * IND; wa = (const float4*)WdA; op = a_d; }
    float x0 = xp[lane], x1 = xp[lane + 64];
    float4 wa0 = wa[lane], wa1 = wa[lane + 64];
    float p0 = x0 * wa0.x + x1 * wa1.x;
    float p1 = x0 * wa0.y + x1 * wa1.y;
    float p2 = x0 * wa0.z + x1 * wa1.z;
    float p3 = x0 * wa0.w + x1 * wa1.w;
    for (int off = 32; off >= 1; off >>= 1) {
        p0 += __shfl_xor(p0, off, 64);
        p1 += __shfl_xor(p1, off, 64);
        p2 += __shfl_xor(p2, off, 64);
        p3 += __shfl_xor(p3, off, 64);
    }
    if (lane == 0) {
        op[n * 4 + 0] = p0; op[n * 4 + 1] = p1;
        op[n * 4 + 2] = p2; op[n * 4 + 3] = p3;
    }
}

// ---------------------------------------------------------------------------
// MFMA GEMM: hs = x @ W_src via f16 MFMA (fp32 acc), output bf16 transposed
// hsTb[n][ch*4+h].  Block = 4 waves x 16 rows = 64 rows; per wave 16x256,
// K=128 whole.  A,B fragments loaded DIRECTLY from global (no LDS).
__global__ __launch_bounds__(256) void gemm_mfma_kernel(
        const float* __restrict__ x, const _Float16* __restrict__ WhT,
        __hip_bfloat16* __restrict__ hsTb) {
    int tid = threadIdx.x;
    int w = tid >> 6, lane = tid & 63;
    int ll = lane & 15, q = lane >> 4;
    int rbase = blockIdx.x * 64 + w * 16;

    // A fragments: lane holds A[m=ll][k=q*8+j] per 32-wide k-chunk
    int arow = rbase + ll;
    if (arow >= N_SRC) arow = N_SRC - 1;           // clamp; stores guarded
    const float* xr = x + (size_t)arow * IND + q * 8;
    half8 afrag[4];
    #pragma unroll
    for (int kf = 0; kf < 4; ++kf) {
        float4 u0 = *(const float4*)(xr + kf * 32);
        float4 u1 = *(const float4*)(xr + kf * 32 + 4);
        half8 a;
        a[0] = (_Float16)u0.x; a[1] = (_Float16)u0.y;
        a[2] = (_Float16)u0.z; a[3] = (_Float16)u0.w;
        a[4] = (_Float16)u1.x; a[5] = (_Float16)u1.y;
        a[6] = (_Float16)u1.z; a[7] = (_Float16)u1.w;
        afrag[kf] = a;
    }

    f32x4 acc[16];
    #pragma unroll
    for (int t = 0; t < 16; ++t) acc[t] = (f32x4){0.f, 0.f, 0.f, 0.f};

    #pragma unroll 2
    for (int t = 0; t < 16; ++t) {
        // B fragment: lane holds B[k=q*8+j][n=ll] ; WhT is [col][k] contiguous
        const _Float16* bp = WhT + (size_t)(t * 16 + ll) * IND + q * 8;
        half8 b0 = *(const half8*)(bp + 0);
        half8 b1 = *(const half8*)(bp + 32);
        half8 b2 = *(const half8*)(bp + 64);
        half8 b3 = *(const half8*)(bp + 96);
        f32x4 c = acc[t];
        c = __builtin_amdgcn_mfma_f32_16x16x32_f16(afrag[0], b0, c, 0, 0, 0);
        c = __builtin_amdgcn_mfma_f32_16x16x32_f16(afrag[1], b1, c, 0, 0, 0);
        c = __builtin_amdgcn_mfma_f32_16x16x32_f16(afrag[2], b2, c, 0, 0, 0);
        c = __builtin_amdgcn_mfma_f32_16x16x32_f16(afrag[3], b3, c, 0, 0, 0);
        acc[t] = c;
    }

    // C/D: reg r of tile t = (row=q*4+r, col=t*16+ll).  Pack heads of tiles
    // {tg,tg+4,tg+8,tg+12} (h=0..3, same ch=tg*16+ll) -> one 8B store.
    #pragma unroll
    for (int tg = 0; tg < 4; ++tg) {
        #pragma unroll
        for (int r = 0; r < 4; ++r) {
            int n = rbase + q * 4 + r;
            if (n < N_SRC) {
                __hip_bfloat16 h0 = __float2bfloat16(acc[tg     ][r]);
                __hip_bfloat16 h1 = __float2bfloat16(acc[tg + 4 ][r]);
                __hip_bfloat16 h2 = __float2bfloat16(acc[tg + 8 ][r]);
                __hip_bfloat16 h3 = __float2bfloat16(acc[tg + 12][r]);
                unsigned int lo = *(unsigned short*)&h0 | ((unsigned int)*(unsigned short*)&h1 << 16);
                unsigned int hi = *(unsigned short*)&h2 | ((unsigned int)*(unsigned short*)&h3 << 16);
                uint2 v = {lo, hi};
                *(uint2*)((unsigned short*)hsTb + (size_t)n * HC + (tg * 16 + ll) * 4) = v;
            }
        }
    }
}

// ---------------------------------------------------------------------------
__global__ void hist_kernel(const int* __restrict__ dst, int* __restrict__ deg) {
    int e = blockIdx.x * 256 + threadIdx.x;
    if (e < NEDGE) atomicAdd(&deg[dst[e]], 1);
}

// ---------------------------------------------------------------------------
__global__ __launch_bounds__(256) void scan_part_kernel(const int* __restrict__ deg,
                                                        int* __restrict__ partial) {
    __shared__ int wsum[4];
    int tid = threadIdx.x, lane = tid & 63, wid = tid >> 6;
    int i0 = blockIdx.x * 1024 + tid * 4;
    int s = 0;
    #pragma unroll
    for (int j = 0; j < 4; ++j) if (i0 + j < N_DST) s += deg[i0 + j];
    for (int off = 32; off >= 1; off >>= 1) s += __shfl_xor(s, off, 64);
    if (lane == 0) wsum[wid] = s;
    __syncthreads();
    if (tid == 0) partial[blockIdx.x] = wsum[0] + wsum[1] + wsum[2] + wsum[3];
}

__global__ void scan_mid_kernel(const int* __restrict__ partial, int* __restrict__ offs,
                                int* __restrict__ row_ptr) {
    int l = threadIdx.x;   // 64 threads
    int v = (l < NB_SCAN) ? partial[l] : 0;
    int x = v;
    for (int off = 1; off < 64; off <<= 1) {
        int u = __shfl_up(x, off, 64);
        if (l >= off) x += u;
    }
    if (l < NB_SCAN) offs[l] = x - v;    // exclusive
    if (l == 0) row_ptr[N_DST] = NEDGE;
}

__global__ __launch_bounds__(256) void scan_write_kernel(const int* __restrict__ deg,
                                                         const int* __restrict__ offs,
                                                         int* __restrict__ row_ptr) {
    __shared__ int wsum[4];
    int tid = threadIdx.x, lane = tid & 63, wid = tid >> 6;
    int i0 = blockIdx.x * 1024 + tid * 4;
    int v0 = (i0 + 0 < N_DST) ? deg[i0 + 0] : 0;
    int v1 = (i0 + 1 < N_DST) ? deg[i0 + 1] : 0;
    int v2 = (i0 + 2 < N_DST) ? deg[i0 + 2] : 0;
    int v3 = (i0 + 3 < N_DST) ? deg[i0 + 3] : 0;
    int t1 = v0, t2 = t1 + v1, t3 = t2 + v2, t4 = t3 + v3;
    int x = t4;
    for (int off = 1; off < 64; off <<= 1) {
        int u = __shfl_up(x, off, 64);
        if (lane >= off) x += u;
    }
    int wave_excl = x - t4;
    if (lane == 63) wsum[wid] = x;
    __syncthreads();
    int woff = 0;
    for (int k = 0; k < wid; ++k) woff += wsum[k];
    int tb = offs[blockIdx.x] + woff + wave_excl;
    if (i0 + 0 < N_DST) row_ptr[i0 + 0] = tb;
    if (i0 + 1 < N_DST) row_ptr[i0 + 1] = tb + t1;
    if (i0 + 2 < N_DST) row_ptr[i0 + 2] = tb + t2;
    if (i0 + 3 < N_DST) row_ptr[i0 + 3] = tb + t3;
}

// ---------------------------------------------------------------------------
__global__ void scatter_kernel(const int* __restrict__ src, const int* __restrict__ dst,
                               const int* __restrict__ row_ptr, int* __restrict__ cnt,
                               int* __restrict__ col,
                               const float4* __restrict__ as4, const float4* __restrict__ ad4,
                               float4* __restrict__ lcsr) {
    int e = blockIdx.x * 256 + threadIdx.x;
    if (e >= NEDGE) return;
    int d = dst[e], s = src[e];
    int pos = row_ptr[d] + atomicAdd(&cnt[d], 1);
    col[pos] = s;
    float4 a = as4[s], b = ad4[d];
    float4 l;
    l.x = a.x + b.x; l.x = l.x > 0.f ? l.x : 0.2f * l.x;
    l.y = a.y + b.y; l.y = l.y > 0.f ? l.y : 0.2f * l.y;
    l.z = a.z + b.z; l.z = l.z > 0.f ? l.z : 0.2f * l.z;
    l.w = a.w + b.w; l.w = l.w > 0.f ? l.w : 0.2f * l.w;
    lcsr[pos] = l;
}

// ---------------------------------------------------------------------------
// One wave per dst node; softmax without max-subtraction (cancels in ratio).
__global__ __launch_bounds__(256) void aggregate_kernel(
        const int* __restrict__ row_ptr, const int* __restrict__ col,
        const float4* __restrict__ lcsr, const __hip_bfloat16* __restrict__ hsTb,
        const float* __restrict__ bias, float* __restrict__ out) {
    int lane = threadIdx.x & 63;
    int i = (blockIdx.x * 256 + threadIdx.x) >> 6;
    if (i >= N_DST) return;
    int beg = row_ptr[i], end = row_ptr[i + 1];
    float bv = bias[lane];
    if (beg == end) { out[i * CDIM + lane] = bv; return; }

    float s0 = 0.f, s1 = 0.f, s2 = 0.f, s3 = 0.f;
    float a0 = 0.f, a1 = 0.f, a2 = 0.f, a3 = 0.f;
    const int myoff = lane << 2;

    for (int cb = beg; cb < end; cb += 64) {
        int e = cb + lane;
        bool valid = e < end;
        int sn = valid ? col[e] : 0;
        float4 l;
        if (valid) l = lcsr[e];
        else       { l.x = -1e30f; l.y = -1e30f; l.z = -1e30f; l.w = -1e30f; }
        float w0 = __expf(l.x), w1 = __expf(l.y), w2 = __expf(l.z), w3 = __expf(l.w);
        s0 += w0; s1 += w1; s2 += w2; s3 += w3;

        int cnt = end - cb; if (cnt > 64) cnt = 64;
        int j = 0;
        for (; j + 2 <= cnt; j += 2) {
            int sA = __shfl(sn, j, 64);
            int sB = __shfl(sn, j + 1, 64);
            uint2 hA = *(const uint2*)((const unsigned short*)hsTb + (size_t)sA * HC + myoff);
            uint2 hB = *(const uint2*)((const unsigned short*)hsTb + (size_t)sB * HC + myoff);
            float wA0 = __shfl(w0, j, 64), wA1 = __shfl(w1, j, 64);
            float wA2 = __shfl(w2, j, 64), wA3 = __shfl(w3, j, 64);
            float wB0 = __shfl(w0, j + 1, 64), wB1 = __shfl(w1, j + 1, 64);
            float wB2 = __shfl(w2, j + 1, 64), wB3 = __shfl(w3, j + 1, 64);
            a0 += wA0 * __uint_as_float(hA.x << 16);
            a1 += wA1 * __uint_as_float(hA.x & 0xffff0000u);
            a2 += wA2 * __uint_as_float(hA.y << 16);
            a3 += wA3 * __uint_as_float(hA.y & 0xffff0000u);
            a0 += wB0 * __uint_as_float(hB.x << 16);
            a1 += wB1 * __uint_as_float(hB.x & 0xffff0000u);
            a2 += wB2 * __uint_as_float(hB.y << 16);
            a3 += wB3 * __uint_as_float(hB.y & 0xffff0000u);
        }
        if (j < cnt) {
            int sA = __shfl(sn, j, 64);
            uint2 hA = *(const uint2*)((const unsigned short*)hsTb + (size_t)sA * HC + myoff);
            float wA0 = __shfl(w0, j, 64), wA1 = __shfl(w1, j, 64);
            float wA2 = __shfl(w2, j, 64), wA3 = __shfl(w3, j, 64);
            a0 += wA0 * __uint_as_float(hA.x << 16);
            a1 += wA1 * __uint_as_float(hA.x & 0xffff0000u);
            a2 += wA2 * __uint_as_float(hA.y << 16);
            a3 += wA3 * __uint_as_float(hA.y & 0xffff0000u);
        }
    }
    for (int off = 32; off >= 1; off >>= 1) {
        s0 += __shfl_xor(s0, off, 64);
        s1 += __shfl_xor(s1, off, 64);
        s2 += __shfl_xor(s2, off, 64);
        s3 += __shfl_xor(s3, off, 64);
    }
    out[i * CDIM + lane] = 0.25f * (a0 / (s0 + 1e-16f) + a1 / (s1 + 1e-16f)
                                  + a2 / (s2 + 1e-16f) + a3 / (s3 + 1e-16f)) + bv;
}

// ---------------------------------------------------------------------------
extern "C" void kernel_launch(void* const* d_in, const int* in_sizes, int n_in,
                              void* d_out, int out_size, void* d_ws, size_t ws_size,
                              hipStream_t stream) {
    const float* x_src   = (const float*)d_in[0];
    const float* x_dst   = (const float*)d_in[1];
    const int*   ei      = (const int*)d_in[2];   // [2][E]: src then dst
    const float* W_src   = (const float*)d_in[3];
    const float* W_dst   = (const float*)d_in[4];
    const float* att_src = (const float*)d_in[5];
    const float* att_dst = (const float*)d_in[6];
    const float* bias    = (const float*)d_in[7];
    float* out = (float*)d_out;

    char* ws = (char*)d_ws;
    __hip_bfloat16* hsTb = (__hip_bfloat16*)ws; ws += (size_t)N_SRC * HC * 2;  // 25.6 MB
    float4* lcsr    = (float4*)ws; ws += (size_t)NEDGE * 16;           // 12.8 MB
    int*    col     = (int*)ws;    ws += (size_t)NEDGE * 4;            // 3.2 MB
    float*  a_s     = (float*)ws;  ws += (size_t)N_SRC * 4 * 4;
    float*  a_d     = (float*)ws;  ws += (size_t)N_DST * 4 * 4;
    float*  WsA     = (float*)ws;  ws += 2048;
    float*  WdA     = (float*)ws;  ws += 2048;
    _Float16* WhT   = (_Float16*)ws; ws += IND * HC * 2;               // 64 KB
    int*    row_ptr = (int*)ws;    ws += 50004 * 4;
    int*    deg     = (int*)ws;    ws += N_DST * 4;
    int*    cnt     = (int*)ws;    ws += N_DST * 4;                    // deg+cnt contiguous
    int*    partial = (int*)ws;    ws += 64 * 4;
    int*    offs    = (int*)ws;    ws += 64 * 4;

    prep_kernel<<<523, 256, 0, stream>>>(W_src, W_dst, att_src, att_dst, WsA, WdA, WhT, deg);
    node_alpha_kernel<<<(2 * N_SRC) / 4, 256, 0, stream>>>(x_src, x_dst, WsA, WdA, a_s, a_d);
    gemm_mfma_kernel<<<(N_SRC + 63) / 64, 256, 0, stream>>>(x_src, WhT, hsTb);
    hist_kernel<<<NEDGE / 256, 256, 0, stream>>>(ei + NEDGE, deg);
    scan_part_kernel<<<NB_SCAN, 256, 0, stream>>>(deg, partial);
    scan_mid_kernel<<<1, 64, 0, stream>>>(partial, offs, row_ptr);
    scan_write_kernel<<<NB_SCAN, 256, 0, stream>>>(deg, offs, row_ptr);
    scatter_kernel<<<NEDGE / 256, 256, 0, stream>>>(ei, ei + NEDGE, row_ptr, cnt, col,
                                                    (const float4*)a_s, (const float4*)a_d, lcsr);
    aggregate_kernel<<<(N_DST + 3) / 4, 256, 0, stream>>>(row_ptr, col, lcsr, hsTb, bias, out);
}

// Round 4
// 307.421 us; speedup vs baseline: 1.1628x; 1.1628x over previous
//
#include <hip/hip_runtime.h>
#include <hip/hip_bf16.h>

#define N_SRC 50000
#define N_DST 50000
#define NEDGE 800000
#define IND   128
#define HEADS 4
#define CDIM  64
#define HC    256   // HEADS*CDIM
#define NB_SCAN 49  // ceil(50000/1024)

typedef _Float16 half8 __attribute__((ext_vector_type(8)));
typedef float    f32x4 __attribute__((ext_vector_type(4)));

// ---------------------------------------------------------------------------
// prep: [0,391) zero deg+cnt; [391,395) fold W·att; [395,523) W_src -> WhT fp16
__global__ void prep_kernel(const float* __restrict__ Wsrc, const float* __restrict__ Wdst,
                            const float* __restrict__ att_s, const float* __restrict__ att_d,
                            float* __restrict__ WsA, float* __restrict__ WdA,
                            _Float16* __restrict__ WhT, int* __restrict__ deg) {
    int b = blockIdx.x, tid = threadIdx.x;
    if (b < 391) {
        int i = b * 256 + tid;
        if (i < 2 * N_DST) deg[i] = 0;
    } else if (b < 395) {
        int id = (b - 391) * 256 + tid;   // 0..1023
        const float* W = (id < 512) ? Wsrc : Wdst;
        const float* A = (id < 512) ? att_s : att_d;
        float* O       = (id < 512) ? WsA  : WdA;
        int q = id & 511;
        int k = q >> 2, h = q & 3;
        float acc = 0.f;
        for (int c = 0; c < CDIM; ++c)
            acc += W[k * HC + h * CDIM + c] * A[h * CDIM + c];
        O[q] = acc;   // q == k*4+h
    } else {
        int idx = (b - 395) * 256 + tid;  // 0..32767, WhT[n][k] = W[k][n]
        int n = idx >> 7, k = idx & 127;
        WhT[idx] = (_Float16)Wsrc[k * HC + n];
    }
}

// ---------------------------------------------------------------------------
// Per-node attention logits: a[n][h] = x[n,:] . WA[:,h].  One wave per node.
__global__ __launch_bounds__(256) void node_alpha_kernel(
        const float* __restrict__ x_src, const float* __restrict__ x_dst,
        const float* __restrict__ WsA, const float* __restrict__ WdA,
        float* __restrict__ a_s, float* __restrict__ a_d) {
    int gw   = (blockIdx.x * 256 + threadIdx.x) >> 6;
    int lane = threadIdx.x & 63;
    const float* xp; const float4* wa; float* op; int n;
    if (gw < N_SRC) { n = gw;         xp = x_src + (size_t)n * IND; wa = (const float4*)WsA; op = a_s; }
    else            { n = gw - N_SRC; xp = x_dst + (size_t)n * IND; wa = (const float4*)WdA; op = a_d; }
    float x0 = xp[lane], x1 = xp[lane + 64];
    float4 wa0 = wa[lane], wa1 = wa[lane + 64];
    float p0 = x0 * wa0.x + x1 * wa1.x;
    float p1 = x0 * wa0.y + x1 * wa1.y;
    float p2 = x0 * wa0.z + x1 * wa1.z;
    float p3 = x0 * wa0.w + x1 * wa1.w;
    for (int off = 32; off >= 1; off >>= 1) {
        p0 += __shfl_xor(p0, off, 64);
        p1 += __shfl_xor(p1, off, 64);
        p2 += __shfl_xor(p2, off, 64);
        p3 += __shfl_xor(p3, off, 64);
    }
    if (lane == 0) {
        op[n * 4 + 0] = p0; op[n * 4 + 1] = p1;
        op[n * 4 + 2] = p2; op[n * 4 + 3] = p3;
    }
}

// ---------------------------------------------------------------------------
// MFMA GEMM: hs = x @ W_src via f16 MFMA (fp32 acc), output bf16 transposed
// hsTb[n][ch*4+h].  Block = 4 waves x 16 rows = 64 rows; per wave 16x256,
// K=128 whole.  A,B fragments loaded DIRECTLY from global (no LDS).
// NOTE: t-loop MUST be fully unrolled — partial unroll leaves acc[t]
// dynamically indexed and the compiler spills all 16 accs to scratch
// (R3: 102 MB of scratch RMW, 9x slowdown).
__global__ __launch_bounds__(256) void gemm_mfma_kernel(
        const float* __restrict__ x, const _Float16* __restrict__ WhT,
        __hip_bfloat16* __restrict__ hsTb) {
    int tid = threadIdx.x;
    int w = tid >> 6, lane = tid & 63;
    int ll = lane & 15, q = lane >> 4;
    int rbase = blockIdx.x * 64 + w * 16;

    // A fragments: lane holds A[m=ll][k=q*8+j] per 32-wide k-chunk
    int arow = rbase + ll;
    if (arow >= N_SRC) arow = N_SRC - 1;           // clamp; stores guarded
    const float* xr = x + (size_t)arow * IND + q * 8;
    half8 afrag[4];
    #pragma unroll
    for (int kf = 0; kf < 4; ++kf) {
        float4 u0 = *(const float4*)(xr + kf * 32);
        float4 u1 = *(const float4*)(xr + kf * 32 + 4);
        half8 a;
        a[0] = (_Float16)u0.x; a[1] = (_Float16)u0.y;
        a[2] = (_Float16)u0.z; a[3] = (_Float16)u0.w;
        a[4] = (_Float16)u1.x; a[5] = (_Float16)u1.y;
        a[6] = (_Float16)u1.z; a[7] = (_Float16)u1.w;
        afrag[kf] = a;
    }

    f32x4 acc[16];
    #pragma unroll
    for (int t = 0; t < 16; ++t) acc[t] = (f32x4){0.f, 0.f, 0.f, 0.f};

    #pragma unroll
    for (int t = 0; t < 16; ++t) {
        // B fragment: lane holds B[k=q*8+j][n=ll] ; WhT is [col][k] contiguous
        const _Float16* bp = WhT + (size_t)(t * 16 + ll) * IND + q * 8;
        half8 b0 = *(const half8*)(bp + 0);
        half8 b1 = *(const half8*)(bp + 32);
        half8 b2 = *(const half8*)(bp + 64);
        half8 b3 = *(const half8*)(bp + 96);
        f32x4 c = acc[t];
        c = __builtin_amdgcn_mfma_f32_16x16x32_f16(afrag[0], b0, c, 0, 0, 0);
        c = __builtin_amdgcn_mfma_f32_16x16x32_f16(afrag[1], b1, c, 0, 0, 0);
        c = __builtin_amdgcn_mfma_f32_16x16x32_f16(afrag[2], b2, c, 0, 0, 0);
        c = __builtin_amdgcn_mfma_f32_16x16x32_f16(afrag[3], b3, c, 0, 0, 0);
        acc[t] = c;
    }

    // C/D: reg r of tile t = (row=q*4+r, col=t*16+ll).  Pack heads of tiles
    // {tg,tg+4,tg+8,tg+12} (h=0..3, same ch=tg*16+ll) -> one 8B store.
    #pragma unroll
    for (int tg = 0; tg < 4; ++tg) {
        #pragma unroll
        for (int r = 0; r < 4; ++r) {
            int n = rbase + q * 4 + r;
            if (n < N_SRC) {
                __hip_bfloat16 h0 = __float2bfloat16(acc[tg     ][r]);
                __hip_bfloat16 h1 = __float2bfloat16(acc[tg + 4 ][r]);
                __hip_bfloat16 h2 = __float2bfloat16(acc[tg + 8 ][r]);
                __hip_bfloat16 h3 = __float2bfloat16(acc[tg + 12][r]);
                unsigned int lo = *(unsigned short*)&h0 | ((unsigned int)*(unsigned short*)&h1 << 16);
                unsigned int hi = *(unsigned short*)&h2 | ((unsigned int)*(unsigned short*)&h3 << 16);
                uint2 v = {lo, hi};
                *(uint2*)((unsigned short*)hsTb + (size_t)n * HC + (tg * 16 + ll) * 4) = v;
            }
        }
    }
}

// ---------------------------------------------------------------------------
__global__ void hist_kernel(const int* __restrict__ dst, int* __restrict__ deg) {
    int e = blockIdx.x * 256 + threadIdx.x;
    if (e < NEDGE) atomicAdd(&deg[dst[e]], 1);
}

// ---------------------------------------------------------------------------
__global__ __launch_bounds__(256) void scan_part_kernel(const int* __restrict__ deg,
                                                        int* __restrict__ partial) {
    __shared__ int wsum[4];
    int tid = threadIdx.x, lane = tid & 63, wid = tid >> 6;
    int i0 = blockIdx.x * 1024 + tid * 4;
    int s = 0;
    #pragma unroll
    for (int j = 0; j < 4; ++j) if (i0 + j < N_DST) s += deg[i0 + j];
    for (int off = 32; off >= 1; off >>= 1) s += __shfl_xor(s, off, 64);
    if (lane == 0) wsum[wid] = s;
    __syncthreads();
    if (tid == 0) partial[blockIdx.x] = wsum[0] + wsum[1] + wsum[2] + wsum[3];
}

__global__ void scan_mid_kernel(const int* __restrict__ partial, int* __restrict__ offs,
                                int* __restrict__ row_ptr) {
    int l = threadIdx.x;   // 64 threads
    int v = (l < NB_SCAN) ? partial[l] : 0;
    int x = v;
    for (int off = 1; off < 64; off <<= 1) {
        int u = __shfl_up(x, off, 64);
        if (l >= off) x += u;
    }
    if (l < NB_SCAN) offs[l] = x - v;    // exclusive
    if (l == 0) row_ptr[N_DST] = NEDGE;
}

__global__ __launch_bounds__(256) void scan_write_kernel(const int* __restrict__ deg,
                                                         const int* __restrict__ offs,
                                                         int* __restrict__ row_ptr) {
    __shared__ int wsum[4];
    int tid = threadIdx.x, lane = tid & 63, wid = tid >> 6;
    int i0 = blockIdx.x * 1024 + tid * 4;
    int v0 = (i0 + 0 < N_DST) ? deg[i0 + 0] : 0;
    int v1 = (i0 + 1 < N_DST) ? deg[i0 + 1] : 0;
    int v2 = (i0 + 2 < N_DST) ? deg[i0 + 2] : 0;
    int v3 = (i0 + 3 < N_DST) ? deg[i0 + 3] : 0;
    int t1 = v0, t2 = t1 + v1, t3 = t2 + v2, t4 = t3 + v3;
    int x = t4;
    for (int off = 1; off < 64; off <<= 1) {
        int u = __shfl_up(x, off, 64);
        if (lane >= off) x += u;
    }
    int wave_excl = x - t4;
    if (lane == 63) wsum[wid] = x;
    __syncthreads();
    int woff = 0;
    for (int k = 0; k < wid; ++k) woff += wsum[k];
    int tb = offs[blockIdx.x] + woff + wave_excl;
    if (i0 + 0 < N_DST) row_ptr[i0 + 0] = tb;
    if (i0 + 1 < N_DST) row_ptr[i0 + 1] = tb + t1;
    if (i0 + 2 < N_DST) row_ptr[i0 + 2] = tb + t2;
    if (i0 + 3 < N_DST) row_ptr[i0 + 3] = tb + t3;
}

// ---------------------------------------------------------------------------
__global__ void scatter_kernel(const int* __restrict__ src, const int* __restrict__ dst,
                               const int* __restrict__ row_ptr, int* __restrict__ cnt,
                               int* __restrict__ col,
                               const float4* __restrict__ as4, const float4* __restrict__ ad4,
                               float4* __restrict__ lcsr) {
    int e = blockIdx.x * 256 + threadIdx.x;
    if (e >= NEDGE) return;
    int d = dst[e], s = src[e];
    int pos = row_ptr[d] + atomicAdd(&cnt[d], 1);
    col[pos] = s;
    float4 a = as4[s], b = ad4[d];
    float4 l;
    l.x = a.x + b.x; l.x = l.x > 0.f ? l.x : 0.2f * l.x;
    l.y = a.y + b.y; l.y = l.y > 0.f ? l.y : 0.2f * l.y;
    l.z = a.z + b.z; l.z = l.z > 0.f ? l.z : 0.2f * l.z;
    l.w = a.w + b.w; l.w = l.w > 0.f ? l.w : 0.2f * l.w;
    lcsr[pos] = l;
}

// ---------------------------------------------------------------------------
// One wave per dst node; softmax without max-subtraction (cancels in ratio).
__global__ __launch_bounds__(256) void aggregate_kernel(
        const int* __restrict__ row_ptr, const int* __restrict__ col,
        const float4* __restrict__ lcsr, const __hip_bfloat16* __restrict__ hsTb,
        const float* __restrict__ bias, float* __restrict__ out) {
    int lane = threadIdx.x & 63;
    int i = (blockIdx.x * 256 + threadIdx.x) >> 6;
    if (i >= N_DST) return;
    int beg = row_ptr[i], end = row_ptr[i + 1];
    float bv = bias[lane];
    if (beg == end) { out[i * CDIM + lane] = bv; return; }

    float s0 = 0.f, s1 = 0.f, s2 = 0.f, s3 = 0.f;
    float a0 = 0.f, a1 = 0.f, a2 = 0.f, a3 = 0.f;
    const int myoff = lane << 2;

    for (int cb = beg; cb < end; cb += 64) {
        int e = cb + lane;
        bool valid = e < end;
        int sn = valid ? col[e] : 0;
        float4 l;
        if (valid) l = lcsr[e];
        else       { l.x = -1e30f; l.y = -1e30f; l.z = -1e30f; l.w = -1e30f; }
        float w0 = __expf(l.x), w1 = __expf(l.y), w2 = __expf(l.z), w3 = __expf(l.w);
        s0 += w0; s1 += w1; s2 += w2; s3 += w3;

        int cnt = end - cb; if (cnt > 64) cnt = 64;
        int j = 0;
        for (; j + 2 <= cnt; j += 2) {
            int sA = __shfl(sn, j, 64);
            int sB = __shfl(sn, j + 1, 64);
            uint2 hA = *(const uint2*)((const unsigned short*)hsTb + (size_t)sA * HC + myoff);
            uint2 hB = *(const uint2*)((const unsigned short*)hsTb + (size_t)sB * HC + myoff);
            float wA0 = __shfl(w0, j, 64), wA1 = __shfl(w1, j, 64);
            float wA2 = __shfl(w2, j, 64), wA3 = __shfl(w3, j, 64);
            float wB0 = __shfl(w0, j + 1, 64), wB1 = __shfl(w1, j + 1, 64);
            float wB2 = __shfl(w2, j + 1, 64), wB3 = __shfl(w3, j + 1, 64);
            a0 += wA0 * __uint_as_float(hA.x << 16);
            a1 += wA1 * __uint_as_float(hA.x & 0xffff0000u);
            a2 += wA2 * __uint_as_float(hA.y << 16);
            a3 += wA3 * __uint_as_float(hA.y & 0xffff0000u);
            a0 += wB0 * __uint_as_float(hB.x << 16);
            a1 += wB1 * __uint_as_float(hB.x & 0xffff0000u);
            a2 += wB2 * __uint_as_float(hB.y << 16);
            a3 += wB3 * __uint_as_float(hB.y & 0xffff0000u);
        }
        if (j < cnt) {
            int sA = __shfl(sn, j, 64);
            uint2 hA = *(const uint2*)((const unsigned short*)hsTb + (size_t)sA * HC + myoff);
            float wA0 = __shfl(w0, j, 64), wA1 = __shfl(w1, j, 64);
            float wA2 = __shfl(w2, j, 64), wA3 = __shfl(w3, j, 64);
            a0 += wA0 * __uint_as_float(hA.x << 16);
            a1 += wA1 * __uint_as_float(hA.x & 0xffff0000u);
            a2 += wA2 * __uint_as_float(hA.y << 16);
            a3 += wA3 * __uint_as_float(hA.y & 0xffff0000u);
        }
    }
    for (int off = 32; off >= 1; off >>= 1) {
        s0 += __shfl_xor(s0, off, 64);
        s1 += __shfl_xor(s1, off, 64);
        s2 += __shfl_xor(s2, off, 64);
        s3 += __shfl_xor(s3, off, 64);
    }
    out[i * CDIM + lane] = 0.25f * (a0 / (s0 + 1e-16f) + a1 / (s1 + 1e-16f)
                                  + a2 / (s2 + 1e-16f) + a3 / (s3 + 1e-16f)) + bv;
}

// ---------------------------------------------------------------------------
extern "C" void kernel_launch(void* const* d_in, const int* in_sizes, int n_in,
                              void* d_out, int out_size, void* d_ws, size_t ws_size,
                              hipStream_t stream) {
    const float* x_src   = (const float*)d_in[0];
    const float* x_dst   = (const float*)d_in[1];
    const int*   ei      = (const int*)d_in[2];   // [2][E]: src then dst
    const float* W_src   = (const float*)d_in[3];
    const float* W_dst   = (const float*)d_in[4];
    const float* att_src = (const float*)d_in[5];
    const float* att_dst = (const float*)d_in[6];
    const float* bias    = (const float*)d_in[7];
    float* out = (float*)d_out;

    char* ws = (char*)d_ws;
    __hip_bfloat16* hsTb = (__hip_bfloat16*)ws; ws += (size_t)N_SRC * HC * 2;  // 25.6 MB
    float4* lcsr    = (float4*)ws; ws += (size_t)NEDGE * 16;           // 12.8 MB
    int*    col     = (int*)ws;    ws += (size_t)NEDGE * 4;            // 3.2 MB
    float*  a_s     = (float*)ws;  ws += (size_t)N_SRC * 4 * 4;
    float*  a_d     = (float*)ws;  ws += (size_t)N_DST * 4 * 4;
    float*  WsA     = (float*)ws;  ws += 2048;
    float*  WdA     = (float*)ws;  ws += 2048;
    _Float16* WhT   = (_Float16*)ws; ws += IND * HC * 2;               // 64 KB
    int*    row_ptr = (int*)ws;    ws += 50004 * 4;
    int*    deg     = (int*)ws;    ws += N_DST * 4;
    int*    cnt     = (int*)ws;    ws += N_DST * 4;                    // deg+cnt contiguous
    int*    partial = (int*)ws;    ws += 64 * 4;
    int*    offs    = (int*)ws;    ws += 64 * 4;

    prep_kernel<<<523, 256, 0, stream>>>(W_src, W_dst, att_src, att_dst, WsA, WdA, WhT, deg);
    node_alpha_kernel<<<(2 * N_SRC) / 4, 256, 0, stream>>>(x_src, x_dst, WsA, WdA, a_s, a_d);
    gemm_mfma_kernel<<<(N_SRC + 63) / 64, 256, 0, stream>>>(x_src, WhT, hsTb);
    hist_kernel<<<NEDGE / 256, 256, 0, stream>>>(ei + NEDGE, deg);
    scan_part_kernel<<<NB_SCAN, 256, 0, stream>>>(deg, partial);
    scan_mid_kernel<<<1, 64, 0, stream>>>(partial, offs, row_ptr);
    scan_write_kernel<<<NB_SCAN, 256, 0, stream>>>(deg, offs, row_ptr);
    scatter_kernel<<<NEDGE / 256, 256, 0, stream>>>(ei, ei + NEDGE, row_ptr, cnt, col,
                                                    (const float4*)a_s, (const float4*)a_d, lcsr);
    aggregate_kernel<<<(N_DST + 3) / 4, 256, 0, stream>>>(row_ptr, col, lcsr, hsTb, bias, out);
}

// Round 5
// 288.237 us; speedup vs baseline: 1.2402x; 1.0666x over previous
//
#include <hip/hip_runtime.h>
#include <hip/hip_bf16.h>

#define N_SRC 50000
#define N_DST 50000
#define NEDGE 800000
#define IND   128
#define HEADS 4
#define CDIM  64
#define HC    256   // HEADS*CDIM
#define NB_SCAN 49  // ceil(50000/1024)

typedef _Float16 half8 __attribute__((ext_vector_type(8)));
typedef float    f32x4 __attribute__((ext_vector_type(4)));

// ---------------------------------------------------------------------------
// prep: [0,391) zero deg+cnt; [391,393) fold W_dst·att_dst; [393,521) WhT fp16
__global__ void prep_kernel(const float* __restrict__ Wdst,
                            const float* __restrict__ att_d,
                            float* __restrict__ WdA,
                            const float* __restrict__ Wsrc,
                            _Float16* __restrict__ WhT, int* __restrict__ deg) {
    int b = blockIdx.x, tid = threadIdx.x;
    if (b < 391) {
        int i = b * 256 + tid;
        if (i < 2 * N_DST) deg[i] = 0;
    } else if (b < 393) {
        int id = (b - 391) * 256 + tid;   // 0..511
        int k = id >> 2, h = id & 3;
        float acc = 0.f;
        for (int c = 0; c < CDIM; ++c)
            acc += Wdst[k * HC + h * CDIM + c] * att_d[h * CDIM + c];
        WdA[id] = acc;   // id == k*4+h
    } else {
        int idx = (b - 393) * 256 + tid;  // 0..32767, WhT[n][k] = W[k][n]
        int n = idx >> 7, k = idx & 127;
        WhT[idx] = (_Float16)Wsrc[k * HC + n];
    }
}

// ---------------------------------------------------------------------------
// Per-DST-node attention logits: a_d[n][h] = x_dst[n,:] . WdA[:,h]. 1 wave/node.
__global__ __launch_bounds__(256) void node_alpha_kernel(
        const float* __restrict__ x_dst, const float* __restrict__ WdA,
        float* __restrict__ a_d) {
    int n    = (blockIdx.x * 256 + threadIdx.x) >> 6;
    int lane = threadIdx.x & 63;
    const float* xp = x_dst + (size_t)n * IND;
    const float4* wa = (const float4*)WdA;
    float x0 = xp[lane], x1 = xp[lane + 64];
    float4 wa0 = wa[lane], wa1 = wa[lane + 64];
    float p0 = x0 * wa0.x + x1 * wa1.x;
    float p1 = x0 * wa0.y + x1 * wa1.y;
    float p2 = x0 * wa0.z + x1 * wa1.z;
    float p3 = x0 * wa0.w + x1 * wa1.w;
    for (int off = 32; off >= 1; off >>= 1) {
        p0 += __shfl_xor(p0, off, 64);
        p1 += __shfl_xor(p1, off, 64);
        p2 += __shfl_xor(p2, off, 64);
        p3 += __shfl_xor(p3, off, 64);
    }
    if (lane == 0) {
        a_d[n * 4 + 0] = p0; a_d[n * 4 + 1] = p1;
        a_d[n * 4 + 2] = p2; a_d[n * 4 + 3] = p3;
    }
}

// ---------------------------------------------------------------------------
// MFMA GEMM: hs = x @ W_src via f16 MFMA (fp32 acc), output bf16 transposed
// hsTb[n][ch*4+h]; ALSO computes a_s[n][h] = sum_c hs[n][h*64+c]*att_s[h][c]
// from the accumulators (h == t>>2 for this tiling).
// NOTE: t-loop MUST be fully unrolled — partial unroll leaves acc[t]
// dynamically indexed and spills all accs to scratch (R3: 9x slowdown).
__global__ __launch_bounds__(256) void gemm_mfma_kernel(
        const float* __restrict__ x, const _Float16* __restrict__ WhT,
        const float* __restrict__ att_s,
        __hip_bfloat16* __restrict__ hsTb, float* __restrict__ a_s) {
    int tid = threadIdx.x;
    int w = tid >> 6, lane = tid & 63;
    int ll = lane & 15, q = lane >> 4;
    int rbase = blockIdx.x * 64 + w * 16;

    // A fragments: lane holds A[m=ll][k=q*8+j] per 32-wide k-chunk
    int arow = rbase + ll;
    if (arow >= N_SRC) arow = N_SRC - 1;           // clamp; stores guarded
    const float* xr = x + (size_t)arow * IND + q * 8;
    half8 afrag[4];
    #pragma unroll
    for (int kf = 0; kf < 4; ++kf) {
        float4 u0 = *(const float4*)(xr + kf * 32);
        float4 u1 = *(const float4*)(xr + kf * 32 + 4);
        half8 a;
        a[0] = (_Float16)u0.x; a[1] = (_Float16)u0.y;
        a[2] = (_Float16)u0.z; a[3] = (_Float16)u0.w;
        a[4] = (_Float16)u1.x; a[5] = (_Float16)u1.y;
        a[6] = (_Float16)u1.z; a[7] = (_Float16)u1.w;
        afrag[kf] = a;
    }

    f32x4 acc[16];
    #pragma unroll
    for (int t = 0; t < 16; ++t) acc[t] = (f32x4){0.f, 0.f, 0.f, 0.f};

    #pragma unroll
    for (int t = 0; t < 16; ++t) {
        const _Float16* bp = WhT + (size_t)(t * 16 + ll) * IND + q * 8;
        half8 b0 = *(const half8*)(bp + 0);
        half8 b1 = *(const half8*)(bp + 32);
        half8 b2 = *(const half8*)(bp + 64);
        half8 b3 = *(const half8*)(bp + 96);
        f32x4 c = acc[t];
        c = __builtin_amdgcn_mfma_f32_16x16x32_f16(afrag[0], b0, c, 0, 0, 0);
        c = __builtin_amdgcn_mfma_f32_16x16x32_f16(afrag[1], b1, c, 0, 0, 0);
        c = __builtin_amdgcn_mfma_f32_16x16x32_f16(afrag[2], b2, c, 0, 0, 0);
        c = __builtin_amdgcn_mfma_f32_16x16x32_f16(afrag[3], b3, c, 0, 0, 0);
        acc[t] = c;
    }

    // C/D: reg r of tile t = (row=q*4+r, col=t*16+ll).  Pack heads of tiles
    // {tg,tg+4,tg+8,tg+12} (h=0..3, same ch=tg*16+ll) -> one 8B store.
    #pragma unroll
    for (int tg = 0; tg < 4; ++tg) {
        #pragma unroll
        for (int r = 0; r < 4; ++r) {
            int n = rbase + q * 4 + r;
            if (n < N_SRC) {
                __hip_bfloat16 h0 = __float2bfloat16(acc[tg     ][r]);
                __hip_bfloat16 h1 = __float2bfloat16(acc[tg + 4 ][r]);
                __hip_bfloat16 h2 = __float2bfloat16(acc[tg + 8 ][r]);
                __hip_bfloat16 h3 = __float2bfloat16(acc[tg + 12][r]);
                unsigned int lo = *(unsigned short*)&h0 | ((unsigned int)*(unsigned short*)&h1 << 16);
                unsigned int hi = *(unsigned short*)&h2 | ((unsigned int)*(unsigned short*)&h3 << 16);
                uint2 v = {lo, hi};
                *(uint2*)((unsigned short*)hsTb + (size_t)n * HC + (tg * 16 + ll) * 4) = v;
            }
        }
    }

    // a_s epilogue: col = t*16+ll, head = t>>2 (ll<16).  Partial per lane,
    // xor-reduce over the 16-lane ll-group, lane ll==0 stores float4.
    float attv[16];
    #pragma unroll
    for (int t = 0; t < 16; ++t) attv[t] = att_s[t * 16 + ll];
    #pragma unroll
    for (int r = 0; r < 4; ++r) {
        float4 p;
        p.x = acc[0][r]*attv[0]  + acc[1][r]*attv[1]  + acc[2][r]*attv[2]  + acc[3][r]*attv[3];
        p.y = acc[4][r]*attv[4]  + acc[5][r]*attv[5]  + acc[6][r]*attv[6]  + acc[7][r]*attv[7];
        p.z = acc[8][r]*attv[8]  + acc[9][r]*attv[9]  + acc[10][r]*attv[10]+ acc[11][r]*attv[11];
        p.w = acc[12][r]*attv[12]+ acc[13][r]*attv[13]+ acc[14][r]*attv[14]+ acc[15][r]*attv[15];
        #pragma unroll
        for (int off = 1; off < 16; off <<= 1) {
            p.x += __shfl_xor(p.x, off, 64);
            p.y += __shfl_xor(p.y, off, 64);
            p.z += __shfl_xor(p.z, off, 64);
            p.w += __shfl_xor(p.w, off, 64);
        }
        int n = rbase + q * 4 + r;
        if (ll == 0 && n < N_SRC) *(float4*)(a_s + (size_t)n * 4) = p;
    }
}

// ---------------------------------------------------------------------------
__global__ void hist_kernel(const int* __restrict__ dst, int* __restrict__ deg) {
    int e = blockIdx.x * 256 + threadIdx.x;
    if (e < NEDGE) atomicAdd(&deg[dst[e]], 1);
}

// ---------------------------------------------------------------------------
__global__ __launch_bounds__(256) void scan_part_kernel(const int* __restrict__ deg,
                                                        int* __restrict__ partial) {
    __shared__ int wsum[4];
    int tid = threadIdx.x, lane = tid & 63, wid = tid >> 6;
    int i0 = blockIdx.x * 1024 + tid * 4;
    int s = 0;
    #pragma unroll
    for (int j = 0; j < 4; ++j) if (i0 + j < N_DST) s += deg[i0 + j];
    for (int off = 32; off >= 1; off >>= 1) s += __shfl_xor(s, off, 64);
    if (lane == 0) wsum[wid] = s;
    __syncthreads();
    if (tid == 0) partial[blockIdx.x] = wsum[0] + wsum[1] + wsum[2] + wsum[3];
}

// scan_write also folds the 49-partial scan (wave 0) — no scan_mid kernel.
__global__ __launch_bounds__(256) void scan_write_kernel(const int* __restrict__ deg,
                                                         const int* __restrict__ partial,
                                                         int* __restrict__ row_ptr) {
    __shared__ int wsum[4];
    __shared__ int block_off;
    int tid = threadIdx.x, lane = tid & 63, wid = tid >> 6;
    if (tid < 64) {
        int v = (lane < NB_SCAN) ? partial[lane] : 0;
        int xx = v;
        for (int off = 1; off < 64; off <<= 1) {
            int u = __shfl_up(xx, off, 64);
            if (lane >= off) xx += u;
        }
        if (lane == blockIdx.x) block_off = xx - v;   // exclusive prefix
    }
    int i0 = blockIdx.x * 1024 + tid * 4;
    int v0 = (i0 + 0 < N_DST) ? deg[i0 + 0] : 0;
    int v1 = (i0 + 1 < N_DST) ? deg[i0 + 1] : 0;
    int v2 = (i0 + 2 < N_DST) ? deg[i0 + 2] : 0;
    int v3 = (i0 + 3 < N_DST) ? deg[i0 + 3] : 0;
    int t1 = v0, t2 = t1 + v1, t3 = t2 + v2, t4 = t3 + v3;
    int x = t4;
    for (int off = 1; off < 64; off <<= 1) {
        int u = __shfl_up(x, off, 64);
        if (lane >= off) x += u;
    }
    int wave_excl = x - t4;
    if (lane == 63) wsum[wid] = x;
    __syncthreads();
    int woff = 0;
    for (int k = 0; k < wid; ++k) woff += wsum[k];
    int tb = block_off + woff + wave_excl;
    if (i0 + 0 < N_DST) row_ptr[i0 + 0] = tb;
    if (i0 + 1 < N_DST) row_ptr[i0 + 1] = tb + t1;
    if (i0 + 2 < N_DST) row_ptr[i0 + 2] = tb + t2;
    if (i0 + 3 < N_DST) row_ptr[i0 + 3] = tb + t3;
    if (blockIdx.x == 0 && tid == 0) row_ptr[N_DST] = NEDGE;
}

// ---------------------------------------------------------------------------
__global__ void scatter_kernel(const int* __restrict__ src, const int* __restrict__ dst,
                               const int* __restrict__ row_ptr, int* __restrict__ cnt,
                               int* __restrict__ col,
                               const float4* __restrict__ as4, const float4* __restrict__ ad4,
                               float4* __restrict__ lcsr) {
    int e = blockIdx.x * 256 + threadIdx.x;
    if (e >= NEDGE) return;
    int d = dst[e], s = src[e];
    int pos = row_ptr[d] + atomicAdd(&cnt[d], 1);
    col[pos] = s;
    float4 a = as4[s], b = ad4[d];
    float4 l;
    l.x = a.x + b.x; l.x = l.x > 0.f ? l.x : 0.2f * l.x;
    l.y = a.y + b.y; l.y = l.y > 0.f ? l.y : 0.2f * l.y;
    l.z = a.z + b.z; l.z = l.z > 0.f ? l.z : 0.2f * l.z;
    l.w = a.w + b.w; l.w = l.w > 0.f ? l.w : 0.2f * l.w;
    lcsr[pos] = l;
}

// ---------------------------------------------------------------------------
// One wave per dst node; softmax without max-subtraction (cancels in ratio).
// Per 64-edge chunk: each lane computes its edge's {offset, w0..w3} and stages
// them in wave-private LDS; the serial j-loop broadcasts via 2 ds_reads
// (replaces 5 __shfl crossbars/edge — R4's DS-pipe bottleneck), with 4
// gathers in flight.
#define ACC8(W, H)                                   \
    a0 += (W).x * __uint_as_float((H).x << 16);      \
    a1 += (W).y * __uint_as_float((H).x & 0xffff0000u); \
    a2 += (W).z * __uint_as_float((H).y << 16);      \
    a3 += (W).w * __uint_as_float((H).y & 0xffff0000u);

__global__ __launch_bounds__(256) void aggregate_kernel(
        const int* __restrict__ row_ptr, const int* __restrict__ col,
        const float4* __restrict__ lcsr, const __hip_bfloat16* __restrict__ hsTb,
        const float* __restrict__ bias, float* __restrict__ out) {
    __shared__ int    s_off[4][64];
    __shared__ float4 s_w[4][64];
    int tid = threadIdx.x;
    int wv = tid >> 6, lane = tid & 63;
    int i = (blockIdx.x * 256 + tid) >> 6;
    if (i >= N_DST) return;
    int beg = row_ptr[i], end = row_ptr[i + 1];
    float bv = bias[lane];
    if (beg == end) { out[i * CDIM + lane] = bv; return; }

    const unsigned short* hb = (const unsigned short*)hsTb + (lane << 2);
    float s0 = 0.f, s1 = 0.f, s2 = 0.f, s3 = 0.f;
    float a0 = 0.f, a1 = 0.f, a2 = 0.f, a3 = 0.f;

    for (int cb = beg; cb < end; cb += 64) {
        int e = cb + lane;
        bool valid = e < end;
        int sn = valid ? col[e] : 0;
        float4 l;
        if (valid) l = lcsr[e];
        float4 wq;
        wq.x = valid ? __expf(l.x) : 0.f;
        wq.y = valid ? __expf(l.y) : 0.f;
        wq.z = valid ? __expf(l.z) : 0.f;
        wq.w = valid ? __expf(l.w) : 0.f;
        s0 += wq.x; s1 += wq.y; s2 += wq.z; s3 += wq.w;
        s_off[wv][lane] = sn * HC;   // ushort-element offset of node row
        s_w[wv][lane]   = wq;
        __asm__ volatile("s_waitcnt lgkmcnt(0)" ::: "memory");

        int cnt = end - cb; if (cnt > 64) cnt = 64;
        int j = 0;
        for (; j + 4 <= cnt; j += 4) {
            int o0 = s_off[wv][j];     float4 q0 = s_w[wv][j];
            int o1 = s_off[wv][j + 1]; float4 q1 = s_w[wv][j + 1];
            int o2 = s_off[wv][j + 2]; float4 q2 = s_w[wv][j + 2];
            int o3 = s_off[wv][j + 3]; float4 q3 = s_w[wv][j + 3];
            uint2 h0 = *(const uint2*)(hb + o0);
            uint2 h1 = *(const uint2*)(hb + o1);
            uint2 h2 = *(const uint2*)(hb + o2);
            uint2 h3 = *(const uint2*)(hb + o3);
            ACC8(q0, h0) ACC8(q1, h1) ACC8(q2, h2) ACC8(q3, h3)
        }
        for (; j < cnt; ++j) {
            int o0 = s_off[wv][j]; float4 q0 = s_w[wv][j];
            uint2 h0 = *(const uint2*)(hb + o0);
            ACC8(q0, h0)
        }
    }
    for (int off = 32; off >= 1; off >>= 1) {
        s0 += __shfl_xor(s0, off, 64);
        s1 += __shfl_xor(s1, off, 64);
        s2 += __shfl_xor(s2, off, 64);
        s3 += __shfl_xor(s3, off, 64);
    }
    out[i * CDIM + lane] = 0.25f * (a0 / (s0 + 1e-16f) + a1 / (s1 + 1e-16f)
                                  + a2 / (s2 + 1e-16f) + a3 / (s3 + 1e-16f)) + bv;
}

// ---------------------------------------------------------------------------
extern "C" void kernel_launch(void* const* d_in, const int* in_sizes, int n_in,
                              void* d_out, int out_size, void* d_ws, size_t ws_size,
                              hipStream_t stream) {
    const float* x_src   = (const float*)d_in[0];
    const float* x_dst   = (const float*)d_in[1];
    const int*   ei      = (const int*)d_in[2];   // [2][E]: src then dst
    const float* W_src   = (const float*)d_in[3];
    const float* W_dst   = (const float*)d_in[4];
    const float* att_src = (const float*)d_in[5];
    const float* att_dst = (const float*)d_in[6];
    const float* bias    = (const float*)d_in[7];
    float* out = (float*)d_out;

    char* ws = (char*)d_ws;
    __hip_bfloat16* hsTb = (__hip_bfloat16*)ws; ws += (size_t)N_SRC * HC * 2;  // 25.6 MB
    float4* lcsr    = (float4*)ws; ws += (size_t)NEDGE * 16;           // 12.8 MB
    int*    col     = (int*)ws;    ws += (size_t)NEDGE * 4;            // 3.2 MB
    float*  a_s     = (float*)ws;  ws += (size_t)N_SRC * 4 * 4;
    float*  a_d     = (float*)ws;  ws += (size_t)N_DST * 4 * 4;
    float*  WdA     = (float*)ws;  ws += 2048;
    _Float16* WhT   = (_Float16*)ws; ws += IND * HC * 2;               // 64 KB
    int*    row_ptr = (int*)ws;    ws += 50004 * 4;
    int*    deg     = (int*)ws;    ws += N_DST * 4;
    int*    cnt     = (int*)ws;    ws += N_DST * 4;                    // deg+cnt contiguous
    int*    partial = (int*)ws;    ws += 64 * 4;

    prep_kernel<<<521, 256, 0, stream>>>(W_dst, att_dst, WdA, W_src, WhT, deg);
    gemm_mfma_kernel<<<(N_SRC + 63) / 64, 256, 0, stream>>>(x_src, WhT, att_src, hsTb, a_s);
    node_alpha_kernel<<<N_DST / 4, 256, 0, stream>>>(x_dst, WdA, a_d);
    hist_kernel<<<NEDGE / 256, 256, 0, stream>>>(ei + NEDGE, deg);
    scan_part_kernel<<<NB_SCAN, 256, 0, stream>>>(deg, partial);
    scan_write_kernel<<<NB_SCAN, 256, 0, stream>>>(deg, partial, row_ptr);
    scatter_kernel<<<NEDGE / 256, 256, 0, stream>>>(ei, ei + NEDGE, row_ptr, cnt, col,
                                                    (const float4*)a_s, (const float4*)a_d, lcsr);
    aggregate_kernel<<<(N_DST + 3) / 4, 256, 0, stream>>>(row_ptr, col, lcsr, hsTb, bias, out);
}

// Round 6
// 261.956 us; speedup vs baseline: 1.3646x; 1.1003x over previous
//
#include <hip/hip_runtime.h>
#include <hip/hip_bf16.h>

#define N_SRC 50000
#define N_DST 50000
#define NEDGE 800000
#define IND   128
#define HEADS 4
#define CDIM  64
#define HC    256   // HEADS*CDIM
#define NB_SCAN 49  // ceil(50000/1024)

typedef _Float16 half8 __attribute__((ext_vector_type(8)));
typedef float    f32x4 __attribute__((ext_vector_type(4)));

// ---------------------------------------------------------------------------
// prep: [0,196) zero deg; [196,198) fold W_dst·att_dst; [198,326) WhT fp16
__global__ void prep_kernel(const float* __restrict__ Wdst,
                            const float* __restrict__ att_d,
                            float* __restrict__ WdA,
                            const float* __restrict__ Wsrc,
                            _Float16* __restrict__ WhT, int* __restrict__ deg) {
    int b = blockIdx.x, tid = threadIdx.x;
    if (b < 196) {
        int i = b * 256 + tid;
        if (i < N_DST) deg[i] = 0;
    } else if (b < 198) {
        int id = (b - 196) * 256 + tid;   // 0..511
        int k = id >> 2, h = id & 3;
        float acc = 0.f;
        for (int c = 0; c < CDIM; ++c)
            acc += Wdst[k * HC + h * CDIM + c] * att_d[h * CDIM + c];
        WdA[id] = acc;   // id == k*4+h
    } else {
        int idx = (b - 198) * 256 + tid;  // 0..32767, WhT[n][k] = W[k][n]
        int n = idx >> 7, k = idx & 127;
        WhT[idx] = (_Float16)Wsrc[k * HC + n];
    }
}

// ---------------------------------------------------------------------------
// Per-DST-node attention logits: a_d[n][h] = x_dst[n,:] . WdA[:,h]. 1 wave/node.
__global__ __launch_bounds__(256) void node_alpha_kernel(
        const float* __restrict__ x_dst, const float* __restrict__ WdA,
        float* __restrict__ a_d) {
    int n    = (blockIdx.x * 256 + threadIdx.x) >> 6;
    int lane = threadIdx.x & 63;
    const float* xp = x_dst + (size_t)n * IND;
    const float4* wa = (const float4*)WdA;
    float x0 = xp[lane], x1 = xp[lane + 64];
    float4 wa0 = wa[lane], wa1 = wa[lane + 64];
    float p0 = x0 * wa0.x + x1 * wa1.x;
    float p1 = x0 * wa0.y + x1 * wa1.y;
    float p2 = x0 * wa0.z + x1 * wa1.z;
    float p3 = x0 * wa0.w + x1 * wa1.w;
    for (int off = 32; off >= 1; off >>= 1) {
        p0 += __shfl_xor(p0, off, 64);
        p1 += __shfl_xor(p1, off, 64);
        p2 += __shfl_xor(p2, off, 64);
        p3 += __shfl_xor(p3, off, 64);
    }
    if (lane == 0) {
        a_d[n * 4 + 0] = p0; a_d[n * 4 + 1] = p1;
        a_d[n * 4 + 2] = p2; a_d[n * 4 + 3] = p3;
    }
}

// ---------------------------------------------------------------------------
// MFMA GEMM: hs = x @ W_src via f16 MFMA (fp32 acc), output bf16 transposed
// hsTb[n][ch*4+h]; ALSO computes a_s[n][h] = sum_c hs[n][h*64+c]*att_s[h][c]
// from the accumulators (h == t>>2 for this tiling).
// NOTE: t-loop MUST be fully unrolled — partial unroll leaves acc[t]
// dynamically indexed and spills all accs to scratch (R3: 9x slowdown).
__global__ __launch_bounds__(256) void gemm_mfma_kernel(
        const float* __restrict__ x, const _Float16* __restrict__ WhT,
        const float* __restrict__ att_s,
        __hip_bfloat16* __restrict__ hsTb, float* __restrict__ a_s) {
    int tid = threadIdx.x;
    int w = tid >> 6, lane = tid & 63;
    int ll = lane & 15, q = lane >> 4;
    int rbase = blockIdx.x * 64 + w * 16;

    // A fragments: lane holds A[m=ll][k=q*8+j] per 32-wide k-chunk
    int arow = rbase + ll;
    if (arow >= N_SRC) arow = N_SRC - 1;           // clamp; stores guarded
    const float* xr = x + (size_t)arow * IND + q * 8;
    half8 afrag[4];
    #pragma unroll
    for (int kf = 0; kf < 4; ++kf) {
        float4 u0 = *(const float4*)(xr + kf * 32);
        float4 u1 = *(const float4*)(xr + kf * 32 + 4);
        half8 a;
        a[0] = (_Float16)u0.x; a[1] = (_Float16)u0.y;
        a[2] = (_Float16)u0.z; a[3] = (_Float16)u0.w;
        a[4] = (_Float16)u1.x; a[5] = (_Float16)u1.y;
        a[6] = (_Float16)u1.z; a[7] = (_Float16)u1.w;
        afrag[kf] = a;
    }

    f32x4 acc[16];
    #pragma unroll
    for (int t = 0; t < 16; ++t) acc[t] = (f32x4){0.f, 0.f, 0.f, 0.f};

    #pragma unroll
    for (int t = 0; t < 16; ++t) {
        const _Float16* bp = WhT + (size_t)(t * 16 + ll) * IND + q * 8;
        half8 b0 = *(const half8*)(bp + 0);
        half8 b1 = *(const half8*)(bp + 32);
        half8 b2 = *(const half8*)(bp + 64);
        half8 b3 = *(const half8*)(bp + 96);
        f32x4 c = acc[t];
        c = __builtin_amdgcn_mfma_f32_16x16x32_f16(afrag[0], b0, c, 0, 0, 0);
        c = __builtin_amdgcn_mfma_f32_16x16x32_f16(afrag[1], b1, c, 0, 0, 0);
        c = __builtin_amdgcn_mfma_f32_16x16x32_f16(afrag[2], b2, c, 0, 0, 0);
        c = __builtin_amdgcn_mfma_f32_16x16x32_f16(afrag[3], b3, c, 0, 0, 0);
        acc[t] = c;
    }

    // C/D: reg r of tile t = (row=q*4+r, col=t*16+ll).  Pack heads of tiles
    // {tg,tg+4,tg+8,tg+12} (h=0..3, same ch=tg*16+ll) -> one 8B store.
    #pragma unroll
    for (int tg = 0; tg < 4; ++tg) {
        #pragma unroll
        for (int r = 0; r < 4; ++r) {
            int n = rbase + q * 4 + r;
            if (n < N_SRC) {
                __hip_bfloat16 h0 = __float2bfloat16(acc[tg     ][r]);
                __hip_bfloat16 h1 = __float2bfloat16(acc[tg + 4 ][r]);
                __hip_bfloat16 h2 = __float2bfloat16(acc[tg + 8 ][r]);
                __hip_bfloat16 h3 = __float2bfloat16(acc[tg + 12][r]);
                unsigned int lo = *(unsigned short*)&h0 | ((unsigned int)*(unsigned short*)&h1 << 16);
                unsigned int hi = *(unsigned short*)&h2 | ((unsigned int)*(unsigned short*)&h3 << 16);
                uint2 v = {lo, hi};
                *(uint2*)((unsigned short*)hsTb + (size_t)n * HC + (tg * 16 + ll) * 4) = v;
            }
        }
    }

    // a_s epilogue: col = t*16+ll, head = t>>2 (ll<16).  Partial per lane,
    // xor-reduce over the 16-lane ll-group, lane ll==0 stores float4.
    float attv[16];
    #pragma unroll
    for (int t = 0; t < 16; ++t) attv[t] = att_s[t * 16 + ll];
    #pragma unroll
    for (int r = 0; r < 4; ++r) {
        float4 p;
        p.x = acc[0][r]*attv[0]  + acc[1][r]*attv[1]  + acc[2][r]*attv[2]  + acc[3][r]*attv[3];
        p.y = acc[4][r]*attv[4]  + acc[5][r]*attv[5]  + acc[6][r]*attv[6]  + acc[7][r]*attv[7];
        p.z = acc[8][r]*attv[8]  + acc[9][r]*attv[9]  + acc[10][r]*attv[10]+ acc[11][r]*attv[11];
        p.w = acc[12][r]*attv[12]+ acc[13][r]*attv[13]+ acc[14][r]*attv[14]+ acc[15][r]*attv[15];
        #pragma unroll
        for (int off = 1; off < 16; off <<= 1) {
            p.x += __shfl_xor(p.x, off, 64);
            p.y += __shfl_xor(p.y, off, 64);
            p.z += __shfl_xor(p.z, off, 64);
            p.w += __shfl_xor(p.w, off, 64);
        }
        int n = rbase + q * 4 + r;
        if (ll == 0 && n < N_SRC) *(float4*)(a_s + (size_t)n * 4) = p;
    }
}

// ---------------------------------------------------------------------------
// hist: rank[e] = this edge's arrival index at its dst (the atomic we must
// pay anyway doubles as the CSR slot assigner — scatter needs no atomic).
__global__ void hist_kernel(const int* __restrict__ dst, int* __restrict__ deg,
                            int* __restrict__ rank) {
    int e = blockIdx.x * 256 + threadIdx.x;
    if (e < NEDGE) rank[e] = atomicAdd(&deg[dst[e]], 1);
}

// ---------------------------------------------------------------------------
__global__ __launch_bounds__(256) void scan_part_kernel(const int* __restrict__ deg,
                                                        int* __restrict__ partial) {
    __shared__ int wsum[4];
    int tid = threadIdx.x, lane = tid & 63, wid = tid >> 6;
    int i0 = blockIdx.x * 1024 + tid * 4;
    int s = 0;
    #pragma unroll
    for (int j = 0; j < 4; ++j) if (i0 + j < N_DST) s += deg[i0 + j];
    for (int off = 32; off >= 1; off >>= 1) s += __shfl_xor(s, off, 64);
    if (lane == 0) wsum[wid] = s;
    __syncthreads();
    if (tid == 0) partial[blockIdx.x] = wsum[0] + wsum[1] + wsum[2] + wsum[3];
}

// scan_write also folds the 49-partial scan (wave 0) — no scan_mid kernel.
__global__ __launch_bounds__(256) void scan_write_kernel(const int* __restrict__ deg,
                                                         const int* __restrict__ partial,
                                                         int* __restrict__ row_ptr) {
    __shared__ int wsum[4];
    __shared__ int block_off;
    int tid = threadIdx.x, lane = tid & 63, wid = tid >> 6;
    if (tid < 64) {
        int v = (lane < NB_SCAN) ? partial[lane] : 0;
        int xx = v;
        for (int off = 1; off < 64; off <<= 1) {
            int u = __shfl_up(xx, off, 64);
            if (lane >= off) xx += u;
        }
        if (lane == blockIdx.x) block_off = xx - v;   // exclusive prefix
    }
    int i0 = blockIdx.x * 1024 + tid * 4;
    int v0 = (i0 + 0 < N_DST) ? deg[i0 + 0] : 0;
    int v1 = (i0 + 1 < N_DST) ? deg[i0 + 1] : 0;
    int v2 = (i0 + 2 < N_DST) ? deg[i0 + 2] : 0;
    int v3 = (i0 + 3 < N_DST) ? deg[i0 + 3] : 0;
    int t1 = v0, t2 = t1 + v1, t3 = t2 + v2, t4 = t3 + v3;
    int x = t4;
    for (int off = 1; off < 64; off <<= 1) {
        int u = __shfl_up(x, off, 64);
        if (lane >= off) x += u;
    }
    int wave_excl = x - t4;
    if (lane == 63) wsum[wid] = x;
    __syncthreads();
    int woff = 0;
    for (int k = 0; k < wid; ++k) woff += wsum[k];
    int tb = block_off + woff + wave_excl;
    if (i0 + 0 < N_DST) row_ptr[i0 + 0] = tb;
    if (i0 + 1 < N_DST) row_ptr[i0 + 1] = tb + t1;
    if (i0 + 2 < N_DST) row_ptr[i0 + 2] = tb + t2;
    if (i0 + 3 < N_DST) row_ptr[i0 + 3] = tb + t3;
    if (blockIdx.x == 0 && tid == 0) row_ptr[N_DST] = NEDGE;
}

// ---------------------------------------------------------------------------
// CSR column fill — no atomics (rank from hist), row_ptr is L2-resident.
__global__ void scatter_kernel(const int* __restrict__ src, const int* __restrict__ dst,
                               const int* __restrict__ row_ptr,
                               const int* __restrict__ rank, int* __restrict__ col) {
    int e = blockIdx.x * 256 + threadIdx.x;
    if (e >= NEDGE) return;
    int d = dst[e];
    col[row_ptr[d] + rank[e]] = src[e];
}

// ---------------------------------------------------------------------------
// One wave per dst node.  Logits computed ON THE FLY from a_s[sn] (800 KB,
// L2-resident random gather) + per-node a_d — the 12.8 MB lcsr array no
// longer exists.  Softmax without max-subtraction (cancels in ratio).
// Per 64-edge chunk: lane stages {row offset, 4 exp-weights} in wave-private
// LDS; serial j-loop broadcasts via 2 ds_reads with 4 gathers in flight.
#define ACC8(W, H)                                   \
    a0 += (W).x * __uint_as_float((H).x << 16);      \
    a1 += (W).y * __uint_as_float((H).x & 0xffff0000u); \
    a2 += (W).z * __uint_as_float((H).y << 16);      \
    a3 += (W).w * __uint_as_float((H).y & 0xffff0000u);

__global__ __launch_bounds__(256) void aggregate_kernel(
        const int* __restrict__ row_ptr, const int* __restrict__ col,
        const float4* __restrict__ as4, const float4* __restrict__ ad4,
        const __hip_bfloat16* __restrict__ hsTb,
        const float* __restrict__ bias, float* __restrict__ out) {
    __shared__ int    s_off[4][64];
    __shared__ float4 s_w[4][64];
    int tid = threadIdx.x;
    int wv = tid >> 6, lane = tid & 63;
    int i = (blockIdx.x * 256 + tid) >> 6;
    if (i >= N_DST) return;
    int beg = row_ptr[i], end = row_ptr[i + 1];
    float bv = bias[lane];
    if (beg == end) { out[i * CDIM + lane] = bv; return; }
    float4 ad = ad4[i];

    const unsigned short* hb = (const unsigned short*)hsTb + (lane << 2);
    float s0 = 0.f, s1 = 0.f, s2 = 0.f, s3 = 0.f;
    float a0 = 0.f, a1 = 0.f, a2 = 0.f, a3 = 0.f;

    for (int cb = beg; cb < end; cb += 64) {
        int e = cb + lane;
        bool valid = e < end;
        int sn = valid ? col[e] : 0;
        float4 av = as4[sn];                       // L2-resident (800 KB)
        float lx = av.x + ad.x; lx = lx > 0.f ? lx : 0.2f * lx;
        float ly = av.y + ad.y; ly = ly > 0.f ? ly : 0.2f * ly;
        float lz = av.z + ad.z; lz = lz > 0.f ? lz : 0.2f * lz;
        float lw = av.w + ad.w; lw = lw > 0.f ? lw : 0.2f * lw;
        float4 wq;
        wq.x = valid ? __expf(lx) : 0.f;
        wq.y = valid ? __expf(ly) : 0.f;
        wq.z = valid ? __expf(lz) : 0.f;
        wq.w = valid ? __expf(lw) : 0.f;
        s0 += wq.x; s1 += wq.y; s2 += wq.z; s3 += wq.w;
        s_off[wv][lane] = sn * HC;   // ushort-element offset of node row
        s_w[wv][lane]   = wq;
        __asm__ volatile("s_waitcnt lgkmcnt(0)" ::: "memory");

        int cnt = end - cb; if (cnt > 64) cnt = 64;
        int j = 0;
        for (; j + 4 <= cnt; j += 4) {
            int o0 = s_off[wv][j];     float4 q0 = s_w[wv][j];
            int o1 = s_off[wv][j + 1]; float4 q1 = s_w[wv][j + 1];
            int o2 = s_off[wv][j + 2]; float4 q2 = s_w[wv][j + 2];
            int o3 = s_off[wv][j + 3]; float4 q3 = s_w[wv][j + 3];
            uint2 h0 = *(const uint2*)(hb + o0);
            uint2 h1 = *(const uint2*)(hb + o1);
            uint2 h2 = *(const uint2*)(hb + o2);
            uint2 h3 = *(const uint2*)(hb + o3);
            ACC8(q0, h0) ACC8(q1, h1) ACC8(q2, h2) ACC8(q3, h3)
        }
        for (; j < cnt; ++j) {
            int o0 = s_off[wv][j]; float4 q0 = s_w[wv][j];
            uint2 h0 = *(const uint2*)(hb + o0);
            ACC8(q0, h0)
        }
    }
    for (int off = 32; off >= 1; off >>= 1) {
        s0 += __shfl_xor(s0, off, 64);
        s1 += __shfl_xor(s1, off, 64);
        s2 += __shfl_xor(s2, off, 64);
        s3 += __shfl_xor(s3, off, 64);
    }
    out[i * CDIM + lane] = 0.25f * (a0 / (s0 + 1e-16f) + a1 / (s1 + 1e-16f)
                                  + a2 / (s2 + 1e-16f) + a3 / (s3 + 1e-16f)) + bv;
}

// ---------------------------------------------------------------------------
extern "C" void kernel_launch(void* const* d_in, const int* in_sizes, int n_in,
                              void* d_out, int out_size, void* d_ws, size_t ws_size,
                              hipStream_t stream) {
    const float* x_src   = (const float*)d_in[0];
    const float* x_dst   = (const float*)d_in[1];
    const int*   ei      = (const int*)d_in[2];   // [2][E]: src then dst
    const float* W_src   = (const float*)d_in[3];
    const float* W_dst   = (const float*)d_in[4];
    const float* att_src = (const float*)d_in[5];
    const float* att_dst = (const float*)d_in[6];
    const float* bias    = (const float*)d_in[7];
    float* out = (float*)d_out;

    char* ws = (char*)d_ws;
    __hip_bfloat16* hsTb = (__hip_bfloat16*)ws; ws += (size_t)N_SRC * HC * 2;  // 25.6 MB
    int*    col     = (int*)ws;    ws += (size_t)NEDGE * 4;            // 3.2 MB
    int*    rank    = (int*)ws;    ws += (size_t)NEDGE * 4;            // 3.2 MB
    float*  a_s     = (float*)ws;  ws += (size_t)N_SRC * 4 * 4;        // 800 KB
    float*  a_d     = (float*)ws;  ws += (size_t)N_DST * 4 * 4;        // 800 KB
    float*  WdA     = (float*)ws;  ws += 2048;
    _Float16* WhT   = (_Float16*)ws; ws += IND * HC * 2;               // 64 KB
    int*    row_ptr = (int*)ws;    ws += 50004 * 4;
    int*    deg     = (int*)ws;    ws += N_DST * 4;
    int*    partial = (int*)ws;    ws += 64 * 4;

    prep_kernel<<<326, 256, 0, stream>>>(W_dst, att_dst, WdA, W_src, WhT, deg);
    gemm_mfma_kernel<<<(N_SRC + 63) / 64, 256, 0, stream>>>(x_src, WhT, att_src, hsTb, a_s);
    node_alpha_kernel<<<N_DST / 4, 256, 0, stream>>>(x_dst, WdA, a_d);
    hist_kernel<<<NEDGE / 256, 256, 0, stream>>>(ei + NEDGE, deg, rank);
    scan_part_kernel<<<NB_SCAN, 256, 0, stream>>>(deg, partial);
    scan_write_kernel<<<NB_SCAN, 256, 0, stream>>>(deg, partial, row_ptr);
    scatter_kernel<<<NEDGE / 256, 256, 0, stream>>>(ei, ei + NEDGE, row_ptr, rank, col);
    aggregate_kernel<<<(N_DST + 3) / 4, 256, 0, stream>>>(row_ptr, col,
                                                          (const float4*)a_s, (const float4*)a_d,
                                                          hsTb, bias, out);
}

// Round 7
// 260.571 us; speedup vs baseline: 1.3718x; 1.0053x over previous
//
#include <hip/hip_runtime.h>
#include <hip/hip_bf16.h>

#define N_SRC 50000
#define N_DST 50000
#define NEDGE 800000
#define IND   128
#define HEADS 4
#define CDIM  64
#define HC    256   // HEADS*CDIM
#define NB_SCAN 49  // ceil(50000/1024)
#define NB_ALPHA 12500   // node_alpha blocks (4 nodes/block)
#define NB_HIST  3125    // hist blocks

typedef _Float16 half8  __attribute__((ext_vector_type(8)));
typedef _Float16 half2t __attribute__((ext_vector_type(2)));
typedef float    f32x4  __attribute__((ext_vector_type(4)));

static __device__ __forceinline__ unsigned int pack2h(float a, float b) {
    union { half2t h; unsigned int u; } v;
    v.h[0] = (_Float16)a; v.h[1] = (_Float16)b;
    return v.u;
}
static __device__ __forceinline__ half2t bits2h(unsigned int u) {
    union { unsigned int u; half2t h; } v; v.u = u; return v.h;
}

// ---------------------------------------------------------------------------
// prep: [0,196) zero deg; [196,198) fold W_dst·att_dst; [198,326) WhT fp16
__global__ void prep_kernel(const float* __restrict__ Wdst,
                            const float* __restrict__ att_d,
                            float* __restrict__ WdA,
                            const float* __restrict__ Wsrc,
                            _Float16* __restrict__ WhT, int* __restrict__ deg) {
    int b = blockIdx.x, tid = threadIdx.x;
    if (b < 196) {
        int i = b * 256 + tid;
        if (i < N_DST) deg[i] = 0;
    } else if (b < 198) {
        int id = (b - 196) * 256 + tid;   // 0..511
        int k = id >> 2, h = id & 3;
        float acc = 0.f;
        for (int c = 0; c < CDIM; ++c)
            acc += Wdst[k * HC + h * CDIM + c] * att_d[h * CDIM + c];
        WdA[id] = acc;   // id == k*4+h
    } else {
        int idx = (b - 198) * 256 + tid;  // 0..32767, WhT[n][k] = W[k][n]
        int n = idx >> 7, k = idx & 127;
        WhT[idx] = (_Float16)Wsrc[k * HC + n];
    }
}

// ---------------------------------------------------------------------------
// MFMA GEMM: hs = x @ W_src via f16 MFMA (fp32 acc), output **f16** transposed
// hsTh[n][ch*4+h]; ALSO computes a_s[n][h] = sum_c hs[n][h*64+c]*att_s[h][c].
// NOTE: t-loop MUST be fully unrolled — partial unroll leaves acc[t]
// dynamically indexed and spills all accs to scratch (R3: 9x slowdown).
__global__ __launch_bounds__(256) void gemm_mfma_kernel(
        const float* __restrict__ x, const _Float16* __restrict__ WhT,
        const float* __restrict__ att_s,
        unsigned short* __restrict__ hsTh, float* __restrict__ a_s) {
    int tid = threadIdx.x;
    int w = tid >> 6, lane = tid & 63;
    int ll = lane & 15, q = lane >> 4;
    int rbase = blockIdx.x * 64 + w * 16;

    int arow = rbase + ll;
    if (arow >= N_SRC) arow = N_SRC - 1;           // clamp; stores guarded
    const float* xr = x + (size_t)arow * IND + q * 8;
    half8 afrag[4];
    #pragma unroll
    for (int kf = 0; kf < 4; ++kf) {
        float4 u0 = *(const float4*)(xr + kf * 32);
        float4 u1 = *(const float4*)(xr + kf * 32 + 4);
        half8 a;
        a[0] = (_Float16)u0.x; a[1] = (_Float16)u0.y;
        a[2] = (_Float16)u0.z; a[3] = (_Float16)u0.w;
        a[4] = (_Float16)u1.x; a[5] = (_Float16)u1.y;
        a[6] = (_Float16)u1.z; a[7] = (_Float16)u1.w;
        afrag[kf] = a;
    }

    f32x4 acc[16];
    #pragma unroll
    for (int t = 0; t < 16; ++t) acc[t] = (f32x4){0.f, 0.f, 0.f, 0.f};

    #pragma unroll
    for (int t = 0; t < 16; ++t) {
        const _Float16* bp = WhT + (size_t)(t * 16 + ll) * IND + q * 8;
        half8 b0 = *(const half8*)(bp + 0);
        half8 b1 = *(const half8*)(bp + 32);
        half8 b2 = *(const half8*)(bp + 64);
        half8 b3 = *(const half8*)(bp + 96);
        f32x4 c = acc[t];
        c = __builtin_amdgcn_mfma_f32_16x16x32_f16(afrag[0], b0, c, 0, 0, 0);
        c = __builtin_amdgcn_mfma_f32_16x16x32_f16(afrag[1], b1, c, 0, 0, 0);
        c = __builtin_amdgcn_mfma_f32_16x16x32_f16(afrag[2], b2, c, 0, 0, 0);
        c = __builtin_amdgcn_mfma_f32_16x16x32_f16(afrag[3], b3, c, 0, 0, 0);
        acc[t] = c;
    }

    // C/D: reg r of tile t = (row=q*4+r, col=t*16+ll).  Pack heads of tiles
    // {tg,tg+4,tg+8,tg+12} (h=0..3, same ch=tg*16+ll) -> one 8B f16 store.
    #pragma unroll
    for (int tg = 0; tg < 4; ++tg) {
        #pragma unroll
        for (int r = 0; r < 4; ++r) {
            int n = rbase + q * 4 + r;
            if (n < N_SRC) {
                uint2 v;
                v.x = pack2h(acc[tg     ][r], acc[tg + 4 ][r]);
                v.y = pack2h(acc[tg + 8 ][r], acc[tg + 12][r]);
                *(uint2*)(hsTh + (size_t)n * HC + (tg * 16 + ll) * 4) = v;
            }
        }
    }

    // a_s epilogue: col = t*16+ll, head = t>>2.  xor-reduce over ll-group.
    float attv[16];
    #pragma unroll
    for (int t = 0; t < 16; ++t) attv[t] = att_s[t * 16 + ll];
    #pragma unroll
    for (int r = 0; r < 4; ++r) {
        float4 p;
        p.x = acc[0][r]*attv[0]  + acc[1][r]*attv[1]  + acc[2][r]*attv[2]  + acc[3][r]*attv[3];
        p.y = acc[4][r]*attv[4]  + acc[5][r]*attv[5]  + acc[6][r]*attv[6]  + acc[7][r]*attv[7];
        p.z = acc[8][r]*attv[8]  + acc[9][r]*attv[9]  + acc[10][r]*attv[10]+ acc[11][r]*attv[11];
        p.w = acc[12][r]*attv[12]+ acc[13][r]*attv[13]+ acc[14][r]*attv[14]+ acc[15][r]*attv[15];
        #pragma unroll
        for (int off = 1; off < 16; off <<= 1) {
            p.x += __shfl_xor(p.x, off, 64);
            p.y += __shfl_xor(p.y, off, 64);
            p.z += __shfl_xor(p.z, off, 64);
            p.w += __shfl_xor(p.w, off, 64);
        }
        int n = rbase + q * 4 + r;
        if (ll == 0 && n < N_SRC) *(float4*)(a_s + (size_t)n * 4) = p;
    }
}

// ---------------------------------------------------------------------------
// Fused: [0,NB_ALPHA) node_alpha (a_d, 1 wave/node); [NB_ALPHA,..) hist/rank.
__global__ __launch_bounds__(256) void mid_kernel(
        const float* __restrict__ x_dst, const float* __restrict__ WdA,
        float* __restrict__ a_d,
        const int* __restrict__ dst, int* __restrict__ deg, int* __restrict__ rank) {
    int b = blockIdx.x, tid = threadIdx.x;
    if (b < NB_ALPHA) {
        int n    = (b * 256 + tid) >> 6;
        int lane = tid & 63;
        const float* xp = x_dst + (size_t)n * IND;
        const float4* wa = (const float4*)WdA;
        float x0 = xp[lane], x1 = xp[lane + 64];
        float4 wa0 = wa[lane], wa1 = wa[lane + 64];
        float p0 = x0 * wa0.x + x1 * wa1.x;
        float p1 = x0 * wa0.y + x1 * wa1.y;
        float p2 = x0 * wa0.z + x1 * wa1.z;
        float p3 = x0 * wa0.w + x1 * wa1.w;
        for (int off = 32; off >= 1; off >>= 1) {
            p0 += __shfl_xor(p0, off, 64);
            p1 += __shfl_xor(p1, off, 64);
            p2 += __shfl_xor(p2, off, 64);
            p3 += __shfl_xor(p3, off, 64);
        }
        if (lane == 0) {
            a_d[n * 4 + 0] = p0; a_d[n * 4 + 1] = p1;
            a_d[n * 4 + 2] = p2; a_d[n * 4 + 3] = p3;
        }
    } else {
        int e = (b - NB_ALPHA) * 256 + tid;
        if (e < NEDGE) rank[e] = atomicAdd(&deg[dst[e]], 1);
    }
}

// ---------------------------------------------------------------------------
__global__ __launch_bounds__(256) void scan_part_kernel(const int* __restrict__ deg,
                                                        int* __restrict__ partial) {
    __shared__ int wsum[4];
    int tid = threadIdx.x, lane = tid & 63, wid = tid >> 6;
    int i0 = blockIdx.x * 1024 + tid * 4;
    int s = 0;
    #pragma unroll
    for (int j = 0; j < 4; ++j) if (i0 + j < N_DST) s += deg[i0 + j];
    for (int off = 32; off >= 1; off >>= 1) s += __shfl_xor(s, off, 64);
    if (lane == 0) wsum[wid] = s;
    __syncthreads();
    if (tid == 0) partial[blockIdx.x] = wsum[0] + wsum[1] + wsum[2] + wsum[3];
}

// scan_write folds the 49-partial scan (wave 0).
__global__ __launch_bounds__(256) void scan_write_kernel(const int* __restrict__ deg,
                                                         const int* __restrict__ partial,
                                                         int* __restrict__ row_ptr) {
    __shared__ int wsum[4];
    __shared__ int block_off;
    int tid = threadIdx.x, lane = tid & 63, wid = tid >> 6;
    if (tid < 64) {
        int v = (lane < NB_SCAN) ? partial[lane] : 0;
        int xx = v;
        for (int off = 1; off < 64; off <<= 1) {
            int u = __shfl_up(xx, off, 64);
            if (lane >= off) xx += u;
        }
        if (lane == blockIdx.x) block_off = xx - v;   // exclusive prefix
    }
    int i0 = blockIdx.x * 1024 + tid * 4;
    int v0 = (i0 + 0 < N_DST) ? deg[i0 + 0] : 0;
    int v1 = (i0 + 1 < N_DST) ? deg[i0 + 1] : 0;
    int v2 = (i0 + 2 < N_DST) ? deg[i0 + 2] : 0;
    int v3 = (i0 + 3 < N_DST) ? deg[i0 + 3] : 0;
    int t1 = v0, t2 = t1 + v1, t3 = t2 + v2, t4 = t3 + v3;
    int x = t4;
    for (int off = 1; off < 64; off <<= 1) {
        int u = __shfl_up(x, off, 64);
        if (lane >= off) x += u;
    }
    int wave_excl = x - t4;
    if (lane == 63) wsum[wid] = x;
    __syncthreads();
    int woff = 0;
    for (int k = 0; k < wid; ++k) woff += wsum[k];
    int tb = block_off + woff + wave_excl;
    if (i0 + 0 < N_DST) row_ptr[i0 + 0] = tb;
    if (i0 + 1 < N_DST) row_ptr[i0 + 1] = tb + t1;
    if (i0 + 2 < N_DST) row_ptr[i0 + 2] = tb + t2;
    if (i0 + 3 < N_DST) row_ptr[i0 + 3] = tb + t3;
    if (blockIdx.x == 0 && tid == 0) row_ptr[N_DST] = NEDGE;
}

// ---------------------------------------------------------------------------
// CSR column fill — no atomics (rank from mid), row_ptr is L2-resident.
__global__ void scatter_kernel(const int* __restrict__ src, const int* __restrict__ dst,
                               const int* __restrict__ row_ptr,
                               const int* __restrict__ rank, int* __restrict__ col) {
    int e = blockIdx.x * 256 + threadIdx.x;
    if (e >= NEDGE) return;
    int d = dst[e];
    col[row_ptr[d] + rank[e]] = src[e];
}

// ---------------------------------------------------------------------------
// One wave per dst node, two passes.
// Pass 1 (cheap, no hsT traffic): denominators s_h from L2-resident a_s/a_d.
// Pass 2: weights pre-normalized (0.25*exp/s) -> f16 pairs; heads merge into
// ONE fp32 accumulator via v_dot2_f32_f16.  Per edge: 1 ds_read_b128 (staged
// {row-offset, w01, w23}), 1 global dwordx2 (4 f16 of hs), 2 fdot2 — ~20
// issue-cyc/edge vs R6's 38 (2 LDS reads + 4 unpack + 4 fmac).
__global__ __launch_bounds__(256) void aggregate_kernel(
        const int* __restrict__ row_ptr, const int* __restrict__ col,
        const float4* __restrict__ as4, const float4* __restrict__ ad4,
        const unsigned short* __restrict__ hsTh,
        const float* __restrict__ bias, float* __restrict__ out) {
    __shared__ uint4 s_pk[4][64];
    int tid = threadIdx.x;
    int wv = tid >> 6, lane = tid & 63;
    int i = (blockIdx.x * 256 + tid) >> 6;
    if (i >= N_DST) return;
    int beg = row_ptr[i], end = row_ptr[i + 1];
    float bv = bias[lane];
    if (beg == end) { out[i * CDIM + lane] = bv; return; }
    float4 ad = ad4[i];

    // ---- pass 1: denominators
    float s0 = 0.f, s1 = 0.f, s2 = 0.f, s3 = 0.f;
    for (int cb = beg; cb < end; cb += 64) {
        int e = cb + lane;
        bool valid = e < end;
        int sn = valid ? col[e] : 0;
        float4 av = as4[sn];
        float lx = av.x + ad.x; lx = lx > 0.f ? lx : 0.2f * lx;
        float ly = av.y + ad.y; ly = ly > 0.f ? ly : 0.2f * ly;
        float lz = av.z + ad.z; lz = lz > 0.f ? lz : 0.2f * lz;
        float lw = av.w + ad.w; lw = lw > 0.f ? lw : 0.2f * lw;
        s0 += valid ? __expf(lx) : 0.f;
        s1 += valid ? __expf(ly) : 0.f;
        s2 += valid ? __expf(lz) : 0.f;
        s3 += valid ? __expf(lw) : 0.f;
    }
    for (int off = 32; off >= 1; off >>= 1) {
        s0 += __shfl_xor(s0, off, 64);
        s1 += __shfl_xor(s1, off, 64);
        s2 += __shfl_xor(s2, off, 64);
        s3 += __shfl_xor(s3, off, 64);
    }
    float i0 = 0.25f / (s0 + 1e-16f);
    float i1 = 0.25f / (s1 + 1e-16f);
    float i2 = 0.25f / (s2 + 1e-16f);
    float i3 = 0.25f / (s3 + 1e-16f);

    // ---- pass 2: gather-accumulate
    const unsigned short* hb = hsTh + (lane << 2);
    float acc = 0.f;
    for (int cb = beg; cb < end; cb += 64) {
        int e = cb + lane;
        bool valid = e < end;
        int sn = valid ? col[e] : 0;
        float4 av = as4[sn];
        float lx = av.x + ad.x; lx = lx > 0.f ? lx : 0.2f * lx;
        float ly = av.y + ad.y; ly = ly > 0.f ? ly : 0.2f * ly;
        float lz = av.z + ad.z; lz = lz > 0.f ? lz : 0.2f * lz;
        float lw = av.w + ad.w; lw = lw > 0.f ? lw : 0.2f * lw;
        float w0 = valid ? __expf(lx) * i0 : 0.f;
        float w1 = valid ? __expf(ly) * i1 : 0.f;
        float w2 = valid ? __expf(lz) * i2 : 0.f;
        float w3 = valid ? __expf(lw) * i3 : 0.f;
        uint4 pk;
        pk.x = (unsigned int)(sn * HC);
        pk.y = pack2h(w0, w1);
        pk.z = pack2h(w2, w3);
        pk.w = 0;
        s_pk[wv][lane] = pk;
        __asm__ volatile("s_waitcnt lgkmcnt(0)" ::: "memory");

        int cnt = end - cb; if (cnt > 64) cnt = 64;
        int j = 0;
        for (; j + 4 <= cnt; j += 4) {
            uint4 p0 = s_pk[wv][j];
            uint4 p1 = s_pk[wv][j + 1];
            uint4 p2 = s_pk[wv][j + 2];
            uint4 p3 = s_pk[wv][j + 3];
            uint2 h0 = *(const uint2*)(hb + p0.x);
            uint2 h1 = *(const uint2*)(hb + p1.x);
            uint2 h2 = *(const uint2*)(hb + p2.x);
            uint2 h3 = *(const uint2*)(hb + p3.x);
            acc = __builtin_amdgcn_fdot2(bits2h(h0.x), bits2h(p0.y), acc, false);
            acc = __builtin_amdgcn_fdot2(bits2h(h0.y), bits2h(p0.z), acc, false);
            acc = __builtin_amdgcn_fdot2(bits2h(h1.x), bits2h(p1.y), acc, false);
            acc = __builtin_amdgcn_fdot2(bits2h(h1.y), bits2h(p1.z), acc, false);
            acc = __builtin_amdgcn_fdot2(bits2h(h2.x), bits2h(p2.y), acc, false);
            acc = __builtin_amdgcn_fdot2(bits2h(h2.y), bits2h(p2.z), acc, false);
            acc = __builtin_amdgcn_fdot2(bits2h(h3.x), bits2h(p3.y), acc, false);
            acc = __builtin_amdgcn_fdot2(bits2h(h3.y), bits2h(p3.z), acc, false);
        }
        for (; j < cnt; ++j) {
            uint4 p0 = s_pk[wv][j];
            uint2 h0 = *(const uint2*)(hb + p0.x);
            acc = __builtin_amdgcn_fdot2(bits2h(h0.x), bits2h(p0.y), acc, false);
            acc = __builtin_amdgcn_fdot2(bits2h(h0.y), bits2h(p0.z), acc, false);
        }
    }
    out[i * CDIM + lane] = acc + bv;
}

// ---------------------------------------------------------------------------
extern "C" void kernel_launch(void* const* d_in, const int* in_sizes, int n_in,
                              void* d_out, int out_size, void* d_ws, size_t ws_size,
                              hipStream_t stream) {
    const float* x_src   = (const float*)d_in[0];
    const float* x_dst   = (const float*)d_in[1];
    const int*   ei      = (const int*)d_in[2];   // [2][E]: src then dst
    const float* W_src   = (const float*)d_in[3];
    const float* W_dst   = (const float*)d_in[4];
    const float* att_src = (const float*)d_in[5];
    const float* att_dst = (const float*)d_in[6];
    const float* bias    = (const float*)d_in[7];
    float* out = (float*)d_out;

    char* ws = (char*)d_ws;
    unsigned short* hsTh = (unsigned short*)ws; ws += (size_t)N_SRC * HC * 2;  // 25.6 MB f16
    int*    col     = (int*)ws;    ws += (size_t)NEDGE * 4;            // 3.2 MB
    int*    rank    = (int*)ws;    ws += (size_t)NEDGE * 4;            // 3.2 MB
    float*  a_s     = (float*)ws;  ws += (size_t)N_SRC * 4 * 4;        // 800 KB
    float*  a_d     = (float*)ws;  ws += (size_t)N_DST * 4 * 4;        // 800 KB
    float*  WdA     = (float*)ws;  ws += 2048;
    _Float16* WhT   = (_Float16*)ws; ws += IND * HC * 2;               // 64 KB
    int*    row_ptr = (int*)ws;    ws += 50004 * 4;
    int*    deg     = (int*)ws;    ws += N_DST * 4;
    int*    partial = (int*)ws;    ws += 64 * 4;

    prep_kernel<<<326, 256, 0, stream>>>(W_dst, att_dst, WdA, W_src, WhT, deg);
    gemm_mfma_kernel<<<(N_SRC + 63) / 64, 256, 0, stream>>>(x_src, WhT, att_src, hsTh, a_s);
    mid_kernel<<<NB_ALPHA + NB_HIST, 256, 0, stream>>>(x_dst, WdA, a_d, ei + NEDGE, deg, rank);
    scan_part_kernel<<<NB_SCAN, 256, 0, stream>>>(deg, partial);
    scan_write_kernel<<<NB_SCAN, 256, 0, stream>>>(deg, partial, row_ptr);
    scatter_kernel<<<NEDGE / 256, 256, 0, stream>>>(ei, ei + NEDGE, row_ptr, rank, col);
    aggregate_kernel<<<(N_DST + 3) / 4, 256, 0, stream>>>(row_ptr, col,
                                                          (const float4*)a_s, (const float4*)a_d,
                                                          hsTh, bias, out);
}